// Round 4
// baseline (246.649 us; speedup 1.0000x reference)
//
#include <hip/hip_runtime.h>

// PointPillars voxelization, MI355X (gfx950). r9 280.3us, r12 PASSED 244.8us.
// Semantics locked: f32 in/out; binning = f32 sub, multiply by IEEE f32
// reciprocal (fl32(1/0.16f)=6.25 exactly — XLA's lowering). DO NOT TOUCH.
// r13: top dispatch is now the harness's 495MB poison fill (72us @86% HBM —
// untouchable). Controllable cuts:
// (1) THRESH 73728->61440 (240*256): occupied-below ~61435 >= 60000 (600-sigma
//     margin on the fixed input; fallback still guarantees exactness).
//     690k -> ~575k returning atomics (rate is count-proportional: r9 26G/s,
//     r12 ~30G/s -> CSTRIDE widening predicted null, skipped).
// (2) k_fused replaces bsumA-hi+bsumB+k_final: one 837-block kernel, two
//     decoupled-lookback scans (rocPRIM pattern; flag|payload in one 32b
//     atomic word, wave-parallel 64-wide window). -2 launches, -2 counts
//     passes.
// (3) k_emit: 4 voxels/block (256 thr, wave per voxel) — 15000 blocks
//     instead of 60000 1-wave blocks.

constexpr int MAXV    = 60000;
constexpr int MAXP    = 64;
constexpr int DF      = 8;
constexpr int NCMAX   = 432 * 496;    // 214272 cells; % 256 == 0
constexpr int NB      = NCMAX / 256;  // 837
constexpr int EMCAP   = 256;          // per-cell ranking cap (observed max ~35)
constexpr int CSTRIDE = 4;            // counter pad: 16B per cell
constexpr int CSR_CAP = 1000000;      // entries; expected ~560k
constexpr int THRESH  = 61440;        // atomic gate; == 240*256
constexpr int NBLO    = THRESH / 256; // 240

typedef float __attribute__((ext_vector_type(4))) f32x4;

struct Geom { float rm[3], ir[3]; int g[3]; };

__device__ __forceinline__ Geom load_geom(const float* __restrict__ vs,
                                          const float* __restrict__ rmin,
                                          const float* __restrict__ rmax) {
  Geom ge;
#pragma unroll
  for (int a = 0; a < 3; ++a) {
    ge.rm[a] = rmin[a];
    ge.ir[a] = 1.0f / vs[a];           // IEEE f32 divide: 1/0.16f -> 6.25 exactly
    ge.g[a]  = (int)rintf((rmax[a] - rmin[a]) * ge.ir[a]);
  }
  return ge;
}

// identical arithmetic to the passing r7 kernel — do not touch
__device__ __forceinline__ bool cell_of(float4 p, const Geom& ge, int& lin) {
  float c[3] = { p.x, p.y, p.z };
  int v[3]; bool ok = true;
#pragma unroll
  for (int a = 0; a < 3; ++a) {
    float q = floorf((c[a] - ge.rm[a]) * ge.ir[a]);
    v[a] = (int)q;
    ok = ok && (q >= 0.0f) && (v[a] < ge.g[a]);
  }
  lin = (v[2] * ge.g[1] + v[1]) * ge.g[0] + v[0];
  return ok && lin >= 0 && lin < NCMAX;
}

// pass 1: padded-histogram atomicAdd, gated to lin < THRESH; persist packed
// (lin<<8|slot) per point. No other atomics (r11 lesson: never a shared line).
__global__ void k_count(const float* __restrict__ pts, int N,
                        const float* __restrict__ vs, const float* __restrict__ rmin,
                        const float* __restrict__ rmax,
                        int* __restrict__ counts, unsigned int* __restrict__ linslot) {
  int i = blockIdx.x * blockDim.x + threadIdx.x;
  if (i >= N) return;
  Geom ge = load_geom(vs, rmin, rmax);
  float4 p = *(const float4*)(pts + (size_t)i * DF);
  unsigned int pack = 0xFFFFFFFFu;
  int lin;
  if (cell_of(p, ge, lin) && lin < THRESH) {
    int slot = atomicAdd(counts + (size_t)lin * CSTRIDE, 1);
    pack = ((unsigned int)lin << 8) | (unsigned int)(slot < 255 ? slot : 255);
  }
  linslot[i] = pack;   // coalesced 4B store
}

// per-block occupancy sums for cells < THRESH (only consumer: k_fallback occ)
__global__ void k_bsumA(const int* __restrict__ counts, int* __restrict__ bsA) {
  __shared__ int s[256];
  int t = threadIdx.x, i = blockIdx.x * 256 + t;
  s[t] = (counts[(size_t)i * CSTRIDE] > 0) ? 1 : 0;
  __syncthreads();
  for (int o = 128; o > 0; o >>= 1) { if (t < o) s[t] += s[t + o]; __syncthreads(); }
  if (t == 0) bsA[blockIdx.x] = s[0];
}

// exactness escape hatch: occ(below THRESH) = sum bsA[0..NBLO). If < MAXV the
// gate was not provably safe — complete the histogram for lin >= THRESH.
// On the bench distribution occ ~= 61435 >= 60000 so this early-exits.
__global__ void k_fallback(const float* __restrict__ pts, int N,
                           const float* __restrict__ vs, const float* __restrict__ rmin,
                           const float* __restrict__ rmax,
                           int* __restrict__ counts, unsigned int* __restrict__ linslot,
                           const int* __restrict__ bsA) {
  __shared__ int s[256];
  int t = threadIdx.x;
  int v = 0;
  for (int j = t; j < NBLO; j += 256) v += bsA[j];
  s[t] = v; __syncthreads();
  for (int o = 128; o > 0; o >>= 1) { if (t < o) s[t] += s[t + o]; __syncthreads(); }
  if (s[0] >= MAXV) return;            // uniform branch, broadcast from LDS
  Geom ge = load_geom(vs, rmin, rmax);
  int t4 = (blockIdx.x * blockDim.x + threadIdx.x) * 4;
  for (int j = 0; j < 4; ++j) {
    int i = t4 + j;
    if (i >= N) break;
    float4 p = *(const float4*)(pts + (size_t)i * DF);
    int lin;
    if (cell_of(p, ge, lin) && lin >= THRESH) {
      int slot = atomicAdd(counts + (size_t)lin * CSTRIDE, 1);
      linslot[i] = ((unsigned int)lin << 8) | (unsigned int)(slot < 255 ? slot : 255);
    }
  }
}

// ---- decoupled lookback (rocPRIM pattern) ----
// status word: bits[31:30] = 0 invalid / 1 aggregate / 2 inclusive-prefix;
// bits[29:0] = value (payload travels with flag in one word -> relaxed ok).
__device__ __forceinline__ int lookback64(unsigned* st, int b, int t) {
  // call from wave 0 (t = lane 0..63); exclusive prefix valid on lane 0.
  int excl = 0;
  int j = b - 1;
  while (j >= 0) {
    int idx = j - t;                   // lane 0 = closest predecessor
    unsigned s;
    do {
      s = __hip_atomic_load(&st[idx < 0 ? 0 : idx], __ATOMIC_RELAXED,
                            __HIP_MEMORY_SCOPE_AGENT);
      if (idx < 0) s = 2u << 30;       // virtual block -1 = PREFIX(0)
    } while (s < (1u << 30));          // spin until AGG or PREFIX
    unsigned long long pf = __ballot(s >= (2u << 30));
    int L = (pf != 0ULL) ? (__ffsll((unsigned long long)pf) - 1) : 64;
    int contrib = (t <= L) ? (int)(s & 0x3FFFFFFFu) : 0;
    for (int o = 32; o > 0; o >>= 1) contrib += __shfl_down(contrib, o);
    if (t == 0) excl += contrib;       // lane 0 holds window sum
    if (L < 64) break;                 // hit a PREFIX -> done (L wave-uniform)
    j -= 64;
  }
  return excl;
}

// fused bsumA-hi + bsumB + k_final: two single-pass scans (occupied -> vid,
// alloc -> base) with decoupled lookback, then the final writes.
__global__ void __launch_bounds__(256)
k_fused(const int* __restrict__ counts,
        unsigned* __restrict__ stA, unsigned* __restrict__ stB,
        int* __restrict__ cellbase, int* __restrict__ vbase,
        int* __restrict__ vcnt,
        float* __restrict__ out_coords, float* __restrict__ out_nump) {
  __shared__ int s[256];
  __shared__ int sh[2];
  int t = threadIdx.x, b = blockIdx.x, i = b * 256 + t;
  int cnt = counts[(size_t)i * CSTRIDE];
  int f = (cnt > 0) ? 1 : 0;
  // phase A: inclusive scan of occupancy flags
  s[t] = f; __syncthreads();
  for (int o = 1; o < 256; o <<= 1) {
    int x = (t >= o) ? s[t - o] : 0;
    __syncthreads(); s[t] += x; __syncthreads();
  }
  int fscan = s[t];
  int ftot  = s[255];
  if (t == 0)
    __hip_atomic_store(&stA[b], (1u << 30) | (unsigned)ftot,
                       __ATOMIC_RELAXED, __HIP_MEMORY_SCOPE_AGENT);
  if (t < 64) {
    int e = lookback64(stA, b, t);
    if (t == 0) {
      __hip_atomic_store(&stA[b], (2u << 30) | (unsigned)(e + ftot),
                         __ATOMIC_RELAXED, __HIP_MEMORY_SCOPE_AGENT);
      sh[0] = e;
    }
  }
  __syncthreads();
  int prefixA = sh[0];
  int vid = prefixA + fscan - f;
  int alloc = (f && vid < MAXV) ? min(cnt, EMCAP) : 0;
  // phase B: inclusive scan of gated allocation
  s[t] = alloc; __syncthreads();
  for (int o = 1; o < 256; o <<= 1) {
    int x = (t >= o) ? s[t - o] : 0;
    __syncthreads(); s[t] += x; __syncthreads();
  }
  int ascan = s[t];
  int atot  = s[255];
  if (t == 0)
    __hip_atomic_store(&stB[b], (1u << 30) | (unsigned)atot,
                       __ATOMIC_RELAXED, __HIP_MEMORY_SCOPE_AGENT);
  if (t < 64) {
    int e = lookback64(stB, b, t);
    if (t == 0) {
      __hip_atomic_store(&stB[b], (2u << 30) | (unsigned)(e + atot),
                         __ATOMIC_RELAXED, __HIP_MEMORY_SCOPE_AGENT);
      sh[1] = e;
    }
  }
  __syncthreads();
  int base = sh[1] + ascan - alloc;
  if (alloc > 0) {
    cellbase[i] = base;
    vbase[vid] = base;
    vcnt[vid] = alloc;                 // = min(cnt, EMCAP)
    int x = i % 432, rest = i / 432, y = rest % 496, z = rest / 496;
    out_coords[(size_t)vid * 3 + 0] = (float)z;   // [z,y,x] as f32
    out_coords[(size_t)vid * 3 + 1] = (float)y;
    out_coords[(size_t)vid * 3 + 2] = (float)x;
    out_nump[vid] = (float)(cnt < MAXP ? cnt : MAXP);
  } else {
    cellbase[i] = -1;
  }
}

// pure stream: 4 packed entries per thread via uint4; no atomics, no binning
__global__ void k_scatter(const unsigned int* __restrict__ linslot, int N,
                          const int* __restrict__ cellbase, int* __restrict__ csr) {
  int t4 = (blockIdx.x * blockDim.x + threadIdx.x) * 4;
  if (t4 + 3 >= N) {   // tail (N % 4 == 0 for 2M, but keep generic)
    for (int i = t4; i < N; ++i) {
      unsigned int pk = linslot[i];
      if (pk == 0xFFFFFFFFu) continue;
      int lin = (int)(pk >> 8), sl = (int)(pk & 255u);
      int b = cellbase[lin];
      if (b < 0 || sl >= EMCAP) continue;
      int pos = b + sl;
      if (pos < CSR_CAP) csr[pos] = i;
    }
    return;
  }
  uint4 pk4 = *(const uint4*)(linslot + t4);
  unsigned int pk[4] = { pk4.x, pk4.y, pk4.z, pk4.w };
#pragma unroll
  for (int j = 0; j < 4; ++j) {
    if (pk[j] == 0xFFFFFFFFu) continue;
    int lin = (int)(pk[j] >> 8), sl = (int)(pk[j] & 255u);
    int b = cellbase[lin];
    if (b < 0 || sl >= EMCAP) continue;
    int pos = b + sl;
    if (pos < CSR_CAP) csr[pos] = t4 + j;
  }
}

// 4 voxels per block, one wave each: rank by original index (stable-sort
// semantics), write all 64 rows (zero-filled past kf) -> no output memset.
// Output write-once/never-read -> nontemporal stores preserve L2/L3 for the
// random point gathers.
__global__ void __launch_bounds__(256)
k_emit(const float* __restrict__ pts,
       const int* __restrict__ vbase, const int* __restrict__ vcnt,
       const int* __restrict__ csr, float* __restrict__ out_vox) {
  int w = threadIdx.x >> 6, t = threadIdx.x & 63;
  int v = blockIdx.x * 4 + w;          // MAXV % 4 == 0
  __shared__ int sidx[4][EMCAP];
  __shared__ int sorted[4][MAXP];
  int kf = vcnt[v];                    // <= EMCAP by construction
  int base = vbase[v];
  sorted[w][t] = -1;
  for (int j = t; j < kf; j += 64) sidx[w][j] = csr[base + j];
  __syncthreads();
  for (int e = t; e < kf; e += 64) {
    int my = sidx[w][e], rank = 0;
    for (int j = 0; j < kf; ++j) rank += (sidx[w][j] < my) ? 1 : 0;
    if (rank < MAXP) sorted[w][rank] = my;   // MAXP lowest-index, ascending
  }
  __syncthreads();
  int pi = sorted[w][t];
  f32x4 a = {0.f, 0.f, 0.f, 0.f};
  f32x4 b = {0.f, 0.f, 0.f, 0.f};
  if (pi >= 0) {
    const f32x4* src = (const f32x4*)(pts + (size_t)pi * DF);
    a = src[0]; b = src[1];
  }
  f32x4* dst = (f32x4*)(out_vox + ((size_t)v * MAXP + t) * DF);
  __builtin_nontemporal_store(a, dst);
  __builtin_nontemporal_store(b, dst + 1);
}

extern "C" void kernel_launch(void* const* d_in, const int* in_sizes, int n_in,
                              void* d_out, int out_size, void* d_ws, size_t ws_size,
                              hipStream_t stream) {
  const float* pts  = (const float*)d_in[0];
  const float* vs   = (const float*)d_in[1];
  const float* rmin = (const float*)d_in[2];
  const float* rmax = (const float*)d_in[3];
  const int N = in_sizes[0] / DF;  // 2,000,000

  // workspace layout (bytes); total 16,777,728 (< proven-safe 17.3 MB)
  char* ws = (char*)d_ws;
  int* counts          = (int*)(ws);                   // NCMAX*16 = 3,428,352
  int* vcnt            = (int*)(ws +  3428352);        // MAXV*4   =   240,000
  int* vbase           = (int*)(ws +  3668352);        // MAXV*4   =   240,000
  int* bsA             = (int*)(ws +  3908352);        //                4,096
  unsigned* stA        = (unsigned*)(ws + 3912448);    // NB*4 pad =     4,096
  unsigned* stB        = (unsigned*)(ws + 3916544);    // NB*4 pad =     4,096
  int* cellbase        = (int*)(ws +  3920640);        // NCMAX*4  =   857,088
  unsigned int* linslot= (unsigned int*)(ws + 4777728);// N*4      = 8,000,000
  int* csr             = (int*)(ws + 12777728);        // CSR_CAP*4= 4,000,000

  float* out_vox    = (float*)d_out;                            // [60000,64,8]
  float* out_coords = (float*)d_out + (size_t)MAXV * MAXP * DF; // [60000,3]
  float* out_nump   = out_coords + (size_t)MAXV * 3;            // [60000]

  // zero counts+vcnt+vbase+bsA+stA+stB (contiguous); coords/nump safety memset.
  // Voxel region of d_out is fully written by k_emit. Lookback statuses MUST
  // be re-zeroed every launch (graph replay includes this node).
  hipMemsetAsync(ws, 0, 3920640, stream);
  hipMemsetAsync((void*)out_coords, 0, (size_t)MAXV * 4 * 4, stream);

  const int nb1 = (N + 255) / 256;          // 7813
  const int nb4 = (N + 1023) / 1024;        // 1954
  k_count   <<<nb1, 256, 0, stream>>>(pts, N, vs, rmin, rmax, counts, linslot);
  k_bsumA   <<<NBLO, 256, 0, stream>>>(counts, bsA);   // cells < THRESH only
  k_fallback<<<nb4, 256, 0, stream>>>(pts, N, vs, rmin, rmax, counts, linslot, bsA);
  k_fused   <<<NB, 256, 0, stream>>>(counts, stA, stB, cellbase, vbase, vcnt,
                                     out_coords, out_nump);
  k_scatter <<<nb4, 256, 0, stream>>>(linslot, N, cellbase, csr);
  k_emit    <<<MAXV / 4, 256, 0, stream>>>(pts, vbase, vcnt, csr, out_vox);
}

// Round 5
// 244.221 us; speedup vs baseline: 1.0099x; 1.0099x over previous
//
#include <hip/hip_runtime.h>

// PointPillars voxelization, MI355X (gfx950). r9 280.3, r12 244.8 (best),
// r13 246.6 (neutral — fused-lookback bundle).
// Semantics locked: f32 in/out; binning = f32 sub, multiply by IEEE f32
// reciprocal (fl32(1/0.16f)=6.25 exactly — XLA's lowering). DO NOT TOUCH.
// r14 = unbundle r13: REVERT k_fused (lookback spin ~= launches saved; r12's
// 3-kernel mid-section is proven), KEEP:
// (1) THRESH 61440 (240*256): occupied-below ~61435 >= 60000; exactness via
//     occ-check + fallback. 690k -> ~575k returning atomics.
// (2) k_emit 4 voxels/block: 64-thr blocks cap at 16 WGs/CU = 16 waves;
//     256-thr blocks reach 32 waves/CU, and 1/4 the block dispatches.
// r11 lesson (standing): NEVER put wave-coalesced atomics on a shared line.

constexpr int MAXV    = 60000;
constexpr int MAXP    = 64;
constexpr int DF      = 8;
constexpr int NCMAX   = 432 * 496;    // 214272 cells; % 256 == 0
constexpr int NB      = NCMAX / 256;  // 837
constexpr int EMCAP   = 256;          // per-cell ranking cap (observed max ~35)
constexpr int CSTRIDE = 4;            // counter pad: 16B per cell
constexpr int CSR_CAP = 1000000;      // entries; expected ~560k
constexpr int THRESH  = 61440;        // atomic gate; == 240*256
constexpr int NBLO    = THRESH / 256; // 240
constexpr int NBHI    = NB - NBLO;    // 597

typedef float __attribute__((ext_vector_type(4))) f32x4;

struct Geom { float rm[3], ir[3]; int g[3]; };

__device__ __forceinline__ Geom load_geom(const float* __restrict__ vs,
                                          const float* __restrict__ rmin,
                                          const float* __restrict__ rmax) {
  Geom ge;
#pragma unroll
  for (int a = 0; a < 3; ++a) {
    ge.rm[a] = rmin[a];
    ge.ir[a] = 1.0f / vs[a];           // IEEE f32 divide: 1/0.16f -> 6.25 exactly
    ge.g[a]  = (int)rintf((rmax[a] - rmin[a]) * ge.ir[a]);
  }
  return ge;
}

// identical arithmetic to the passing r7 kernel — do not touch
__device__ __forceinline__ bool cell_of(float4 p, const Geom& ge, int& lin) {
  float c[3] = { p.x, p.y, p.z };
  int v[3]; bool ok = true;
#pragma unroll
  for (int a = 0; a < 3; ++a) {
    float q = floorf((c[a] - ge.rm[a]) * ge.ir[a]);
    v[a] = (int)q;
    ok = ok && (q >= 0.0f) && (v[a] < ge.g[a]);
  }
  lin = (v[2] * ge.g[1] + v[1]) * ge.g[0] + v[0];
  return ok && lin >= 0 && lin < NCMAX;
}

// pass 1: padded-histogram atomicAdd, gated to lin < THRESH; persist packed
// (lin<<8|slot) per point. No other atomics.
__global__ void k_count(const float* __restrict__ pts, int N,
                        const float* __restrict__ vs, const float* __restrict__ rmin,
                        const float* __restrict__ rmax,
                        int* __restrict__ counts, unsigned int* __restrict__ linslot) {
  int i = blockIdx.x * blockDim.x + threadIdx.x;
  if (i >= N) return;
  Geom ge = load_geom(vs, rmin, rmax);
  float4 p = *(const float4*)(pts + (size_t)i * DF);
  unsigned int pack = 0xFFFFFFFFu;
  int lin;
  if (cell_of(p, ge, lin) && lin < THRESH) {
    int slot = atomicAdd(counts + (size_t)lin * CSTRIDE, 1);
    pack = ((unsigned int)lin << 8) | (unsigned int)(slot < 255 ? slot : 255);
  }
  linslot[i] = pack;   // coalesced 4B store
}

// per-block occupancy sums over [off*256, (off+nblk)*256) (raw, not scanned)
__global__ void k_bsumA(const int* __restrict__ counts, int* __restrict__ bsA,
                        int off) {
  __shared__ int s[256];
  int t = threadIdx.x, b = blockIdx.x + off, i = b * 256 + t;
  s[t] = (counts[(size_t)i * CSTRIDE] > 0) ? 1 : 0;
  __syncthreads();
  for (int o = 128; o > 0; o >>= 1) { if (t < o) s[t] += s[t + o]; __syncthreads(); }
  if (t == 0) bsA[b] = s[0];
}

// exactness escape hatch: occ(below THRESH) = sum bsA[0..NBLO). If < MAXV the
// gate was not provably safe — complete the histogram for lin >= THRESH.
// On the bench distribution occ ~= 61435 >= 60000 so this early-exits.
__global__ void k_fallback(const float* __restrict__ pts, int N,
                           const float* __restrict__ vs, const float* __restrict__ rmin,
                           const float* __restrict__ rmax,
                           int* __restrict__ counts, unsigned int* __restrict__ linslot,
                           const int* __restrict__ bsA) {
  __shared__ int s[256];
  int t = threadIdx.x;
  int v = 0;
  for (int j = t; j < NBLO; j += 256) v += bsA[j];
  s[t] = v; __syncthreads();
  for (int o = 128; o > 0; o >>= 1) { if (t < o) s[t] += s[t + o]; __syncthreads(); }
  if (s[0] >= MAXV) return;            // uniform branch, broadcast from LDS
  Geom ge = load_geom(vs, rmin, rmax);
  int t4 = (blockIdx.x * blockDim.x + threadIdx.x) * 4;
  for (int j = 0; j < 4; ++j) {
    int i = t4 + j;
    if (i >= N) break;
    float4 p = *(const float4*)(pts + (size_t)i * DF);
    int lin;
    if (cell_of(p, ge, lin) && lin >= THRESH) {
      int slot = atomicAdd(counts + (size_t)lin * CSTRIDE, 1);
      linslot[i] = ((unsigned int)lin << 8) | (unsigned int)(slot < 255 ? slot : 255);
    }
  }
}

// per-block sums of GATED allocation: min(cnt,EMCAP) only for vid < MAXV.
// Global prefix of bsA computed inline (<=837 entries, L2-hot).
__global__ void k_bsumB(const int* __restrict__ counts, const int* __restrict__ bsA,
                        int* __restrict__ bsB) {
  __shared__ int sp[256];
  __shared__ int s[256];
  int t = threadIdx.x, b = blockIdx.x, i = b * 256 + t;
  int pa = 0;
  for (int j = t; j < b; j += 256) pa += bsA[j];
  sp[t] = pa; __syncthreads();
  for (int off = 128; off > 0; off >>= 1) { if (t < off) sp[t] += sp[t + off]; __syncthreads(); }
  int prefixA = sp[0];
  int cnt = counts[(size_t)i * CSTRIDE];
  int f = (cnt > 0) ? 1 : 0;
  s[t] = f; __syncthreads();
  for (int off = 1; off < 256; off <<= 1) {
    int x = (t >= off) ? s[t - off] : 0;
    __syncthreads(); s[t] += x; __syncthreads();
  }
  int vid = prefixA + s[t] - f;
  int alloc = (f && vid < MAXV) ? min(cnt, EMCAP) : 0;
  __syncthreads();
  s[t] = alloc; __syncthreads();
  for (int off = 128; off > 0; off >>= 1) { if (t < off) s[t] += s[t + off]; __syncthreads(); }
  if (t == 0) bsB[blockIdx.x] = s[0];
}

__global__ void k_final(const int* __restrict__ counts, const int* __restrict__ bsA,
                        const int* __restrict__ bsB,
                        int* __restrict__ cellbase, int* __restrict__ vbase,
                        int* __restrict__ vcnt,
                        float* __restrict__ out_coords, float* __restrict__ out_nump) {
  __shared__ int sp[256], so[256], sk[256];
  int t = threadIdx.x, b = blockIdx.x, i = b * 256 + t;
  int pa = 0, pb = 0;
  for (int j = t; j < b; j += 256) { pa += bsA[j]; pb += bsB[j]; }
  sp[t] = pa; __syncthreads();
  for (int off = 128; off > 0; off >>= 1) { if (t < off) sp[t] += sp[t + off]; __syncthreads(); }
  int prefixA = sp[0]; __syncthreads();
  sp[t] = pb; __syncthreads();
  for (int off = 128; off > 0; off >>= 1) { if (t < off) sp[t] += sp[t + off]; __syncthreads(); }
  int prefixB = sp[0];
  int cnt = counts[(size_t)i * CSTRIDE];
  int f = (cnt > 0) ? 1 : 0;
  so[t] = f; __syncthreads();
  for (int off = 1; off < 256; off <<= 1) {
    int x = (t >= off) ? so[t - off] : 0;
    __syncthreads(); so[t] += x; __syncthreads();
  }
  int vid = prefixA + so[t] - f;
  int alloc = (f && vid < MAXV) ? min(cnt, EMCAP) : 0;
  sk[t] = alloc; __syncthreads();
  for (int off = 1; off < 256; off <<= 1) {
    int x = (t >= off) ? sk[t - off] : 0;
    __syncthreads(); sk[t] += x; __syncthreads();
  }
  int base = prefixB + sk[t] - alloc;
  if (alloc > 0) {
    cellbase[i] = base;
    vbase[vid] = base;
    vcnt[vid] = alloc;                 // = min(cnt, EMCAP)
    int x = i % 432, rest = i / 432, y = rest % 496, z = rest / 496;
    out_coords[(size_t)vid * 3 + 0] = (float)z;   // [z,y,x] as f32
    out_coords[(size_t)vid * 3 + 1] = (float)y;
    out_coords[(size_t)vid * 3 + 2] = (float)x;
    out_nump[vid] = (float)(cnt < MAXP ? cnt : MAXP);
  } else {
    cellbase[i] = -1;
  }
}

// pure stream: 4 packed entries per thread via uint4; no atomics, no binning
__global__ void k_scatter(const unsigned int* __restrict__ linslot, int N,
                          const int* __restrict__ cellbase, int* __restrict__ csr) {
  int t4 = (blockIdx.x * blockDim.x + threadIdx.x) * 4;
  if (t4 + 3 >= N) {   // tail (N % 4 == 0 for 2M, but keep generic)
    for (int i = t4; i < N; ++i) {
      unsigned int pk = linslot[i];
      if (pk == 0xFFFFFFFFu) continue;
      int lin = (int)(pk >> 8), sl = (int)(pk & 255u);
      int b = cellbase[lin];
      if (b < 0 || sl >= EMCAP) continue;
      int pos = b + sl;
      if (pos < CSR_CAP) csr[pos] = i;
    }
    return;
  }
  uint4 pk4 = *(const uint4*)(linslot + t4);
  unsigned int pk[4] = { pk4.x, pk4.y, pk4.z, pk4.w };
#pragma unroll
  for (int j = 0; j < 4; ++j) {
    if (pk[j] == 0xFFFFFFFFu) continue;
    int lin = (int)(pk[j] >> 8), sl = (int)(pk[j] & 255u);
    int b = cellbase[lin];
    if (b < 0 || sl >= EMCAP) continue;
    int pos = b + sl;
    if (pos < CSR_CAP) csr[pos] = t4 + j;
  }
}

// 4 voxels per block, one wave each: rank by original index (stable-sort
// semantics), write all 64 rows (zero-filled past kf) -> no output memset.
// Output write-once/never-read -> nontemporal stores preserve L2/L3 for the
// random point gathers.
__global__ void __launch_bounds__(256)
k_emit(const float* __restrict__ pts,
       const int* __restrict__ vbase, const int* __restrict__ vcnt,
       const int* __restrict__ csr, float* __restrict__ out_vox) {
  int w = threadIdx.x >> 6, t = threadIdx.x & 63;
  int v = blockIdx.x * 4 + w;          // MAXV % 4 == 0
  __shared__ int sidx[4][EMCAP];
  __shared__ int sorted[4][MAXP];
  int kf = vcnt[v];                    // <= EMCAP by construction
  int base = vbase[v];
  sorted[w][t] = -1;
  for (int j = t; j < kf; j += 64) sidx[w][j] = csr[base + j];
  __syncthreads();
  for (int e = t; e < kf; e += 64) {
    int my = sidx[w][e], rank = 0;
    for (int j = 0; j < kf; ++j) rank += (sidx[w][j] < my) ? 1 : 0;
    if (rank < MAXP) sorted[w][rank] = my;   // MAXP lowest-index, ascending
  }
  __syncthreads();
  int pi = sorted[w][t];
  f32x4 a = {0.f, 0.f, 0.f, 0.f};
  f32x4 b = {0.f, 0.f, 0.f, 0.f};
  if (pi >= 0) {
    const f32x4* src = (const f32x4*)(pts + (size_t)pi * DF);
    a = src[0]; b = src[1];
  }
  f32x4* dst = (f32x4*)(out_vox + ((size_t)v * MAXP + t) * DF);
  __builtin_nontemporal_store(a, dst);
  __builtin_nontemporal_store(b, dst + 1);
}

extern "C" void kernel_launch(void* const* d_in, const int* in_sizes, int n_in,
                              void* d_out, int out_size, void* d_ws, size_t ws_size,
                              hipStream_t stream) {
  const float* pts  = (const float*)d_in[0];
  const float* vs   = (const float*)d_in[1];
  const float* rmin = (const float*)d_in[2];
  const float* rmax = (const float*)d_in[3];
  const int N = in_sizes[0] / DF;  // 2,000,000

  // workspace layout (bytes); total 16,773,632 (< proven-safe 17.3 MB)
  char* ws = (char*)d_ws;
  int* counts          = (int*)(ws);                   // NCMAX*16 = 3,428,352
  int* vcnt            = (int*)(ws +  3428352);        // MAXV*4   =   240,000
  int* vbase           = (int*)(ws +  3668352);        // MAXV*4   =   240,000
  int* bsA             = (int*)(ws +  3908352);        //                4,096
  int* bsB             = (int*)(ws +  3912448);        //                4,096
  int* cellbase        = (int*)(ws +  3916544);        // NCMAX*4  =   857,088
  unsigned int* linslot= (unsigned int*)(ws + 4773632);// N*4      = 8,000,000
  int* csr             = (int*)(ws + 12773632);        // CSR_CAP*4= 4,000,000

  float* out_vox    = (float*)d_out;                            // [60000,64,8]
  float* out_coords = (float*)d_out + (size_t)MAXV * MAXP * DF; // [60000,3]
  float* out_nump   = out_coords + (size_t)MAXV * 3;            // [60000]

  // zero counts+vcnt+vbase (contiguous); coords/nump safety memset (0.96 MB).
  // Voxel region of d_out is fully written by k_emit.
  hipMemsetAsync(ws, 0, 3908352, stream);
  hipMemsetAsync((void*)out_coords, 0, (size_t)MAXV * 4 * 4, stream);

  const int nb1 = (N + 255) / 256;          // 7813
  const int nb4 = (N + 1023) / 1024;        // 1954
  k_count   <<<nb1, 256, 0, stream>>>(pts, N, vs, rmin, rmax, counts, linslot);
  k_bsumA   <<<NBLO, 256, 0, stream>>>(counts, bsA, 0);      // cells < THRESH
  k_fallback<<<nb4, 256, 0, stream>>>(pts, N, vs, rmin, rmax, counts, linslot, bsA);
  k_bsumA   <<<NBHI, 256, 0, stream>>>(counts, bsA, NBLO);   // cells >= THRESH
  k_bsumB   <<<NB, 256, 0, stream>>>(counts, bsA, bsB);
  k_final   <<<NB, 256, 0, stream>>>(counts, bsA, bsB, cellbase, vbase, vcnt,
                                     out_coords, out_nump);
  k_scatter <<<nb4, 256, 0, stream>>>(linslot, N, cellbase, csr);
  k_emit    <<<MAXV / 4, 256, 0, stream>>>(pts, vbase, vcnt, csr, out_vox);
}